// Round 10
// baseline (7590.501 us; speedup 1.0000x reference)
//
#include <hip/hip_runtime.h>
#include <math.h>

#define VOCAB 32000
#define HID   1024
#define BATCH 8
#define SEQ   512
#define GD    (4*HID)       // 4096 gate width
#define ROWS  (BATCH*SEQ)   // 4096

typedef __attribute__((ext_vector_type(8))) short short8;
typedef __attribute__((ext_vector_type(4))) float f32x4;

__device__ __forceinline__ float hi_f32(float x) {
    return __uint_as_float(__float_as_uint(x) & 0xFFFF0000u);
}
// packed word: hi bf16 bits in high half, lo bf16 bits in low half
__device__ __forceinline__ unsigned pack_pair(float x) {
    unsigned hb = __float_as_uint(x) & 0xFFFF0000u;
    float lo = x - __uint_as_float(hb);
    return hb | (__float_as_uint(lo) >> 16);
}
__device__ __forceinline__ unsigned pack_hi2(float x, float y) {
    return (__float_as_uint(x) >> 16) | (__float_as_uint(y) & 0xFFFF0000u);
}

// async 16B/lane global->LDS (dest = wave-uniform base + lane*16)
__device__ __forceinline__ void gload16(const void* g, void* l) {
    __builtin_amdgcn_global_load_lds(
        (__attribute__((address_space(1))) void*)g,
        (__attribute__((address_space(3))) void*)l, 16, 0, 0);
}

// ---------------------------------------------------------------------------
// 1) Embedding gather, split: emb_hi/lo[row][h] = split(w_out[h][ids[row]])
// ---------------------------------------------------------------------------
__global__ __launch_bounds__(256) void k_gather_split(const int* __restrict__ ids,
                                                      const float* __restrict__ w_out,
                                                      unsigned short* __restrict__ emb_hi,
                                                      unsigned short* __restrict__ emb_lo)
{
    int row = blockIdx.x;            // 0..4095
    int id  = ids[row];
    const float* src = w_out + id;   // column id, stride VOCAB
    for (int h = threadIdx.x; h < HID; h += 256) {
        float v  = src[(size_t)h * VOCAB];
        float lo = v - hi_f32(v);
        emb_hi[(size_t)row*HID + h] = (unsigned short)(__float_as_uint(v)  >> 16);
        emb_lo[(size_t)row*HID + h] = (unsigned short)(__float_as_uint(lo) >> 16);
    }
}

// ---------------------------------------------------------------------------
// 2) Transpose W_hh [1024][4096] -> W_hhT [4096][1024] (fp32, for the scan)
// ---------------------------------------------------------------------------
__global__ __launch_bounds__(256) void k_transpose(const float* __restrict__ W,
                                                   float* __restrict__ WT)
{
    __shared__ float tile[32][33];
    int tx = threadIdx.x, ty = threadIdx.y;
    int x = blockIdx.x*32 + tx;
    int y = blockIdx.y*32 + ty;
    #pragma unroll
    for (int i = 0; i < 32; i += 8)
        tile[ty + i][tx] = W[(size_t)(y + i)*GD + x];
    __syncthreads();
    int k   = blockIdx.y*32 + tx;
    int col = blockIdx.x*32 + ty;
    #pragma unroll
    for (int i = 0; i < 32; i += 8)
        WT[(size_t)(col + i)*HID + k] = tile[tx][ty + i];
}

// ---------------------------------------------------------------------------
// 2b) Transpose + split: W[K=1024][N] f32 -> hiT/loT[N][1024] bf16 bits
// ---------------------------------------------------------------------------
__global__ __launch_bounds__(256) void k_transsplit(const float* __restrict__ W,
                                                    unsigned short* __restrict__ hiT,
                                                    unsigned short* __restrict__ loT,
                                                    int N)
{
    __shared__ float tile[32][33];
    int tx = threadIdx.x, ty = threadIdx.y;
    int x = blockIdx.x*32 + tx;      // N
    int y = blockIdx.y*32 + ty;      // K
    #pragma unroll
    for (int i = 0; i < 32; i += 8)
        tile[ty + i][tx] = W[(size_t)(y + i)*N + x];
    __syncthreads();
    int n = blockIdx.x*32 + ty;
    int k = blockIdx.y*32 + tx;
    #pragma unroll
    for (int i = 0; i < 32; i += 8) {
        float v  = tile[tx][ty + i];
        float lo = v - hi_f32(v);
        hiT[(size_t)(n + i)*HID + k] = (unsigned short)(__float_as_uint(v)  >> 16);
        loT[(size_t)(n + i)*HID + k] = (unsigned short)(__float_as_uint(lo) >> 16);
    }
}

// ---------------------------------------------------------------------------
// 2c) Split fp32 -> hi bf16, lo bf16 arrays (grid-stride, float4)
// ---------------------------------------------------------------------------
__global__ __launch_bounds__(256) void k_split_f32(const float* __restrict__ src,
                                                   unsigned short* __restrict__ hi,
                                                   unsigned short* __restrict__ lo,
                                                   long n4)
{
    long i0 = (long)blockIdx.x * 256 + threadIdx.x;
    long stride = (long)gridDim.x * 256;
    for (long i = i0; i < n4; i += stride) {
        float4 v = ((const float4*)src)[i];
        unsigned h0 = __float_as_uint(v.x) >> 16, h1 = __float_as_uint(v.y) >> 16;
        unsigned h2 = __float_as_uint(v.z) >> 16, h3 = __float_as_uint(v.w) >> 16;
        unsigned l0 = __float_as_uint(v.x - hi_f32(v.x)) >> 16;
        unsigned l1 = __float_as_uint(v.y - hi_f32(v.y)) >> 16;
        unsigned l2 = __float_as_uint(v.z - hi_f32(v.z)) >> 16;
        unsigned l3 = __float_as_uint(v.w - hi_f32(v.w)) >> 16;
        ((uint2*)hi)[i] = make_uint2(h0 | (h1 << 16), h2 | (h3 << 16));
        ((uint2*)lo)[i] = make_uint2(l0 | (l1 << 16), l2 | (l3 << 16));
    }
}

// ---------------------------------------------------------------------------
// 3) Fast split-bf16 MFMA GEMM, all operands K-major bf16 bits (R8 proven).
// ---------------------------------------------------------------------------
#define GBM 128
#define GBN 128
#define GBK 32

__global__ __launch_bounds__(256) void k_gemm_fast(
    const unsigned short* __restrict__ Ah,  const unsigned short* __restrict__ Al,
    const unsigned short* __restrict__ BhT, const unsigned short* __restrict__ BlT,
    const float* __restrict__ bias, float* __restrict__ C,
    int M, int N, int K)
{
    __shared__ __align__(16) unsigned short lds[4][4096];  // Ah,Al,Bh,Bl: 8KB each

    const int tid  = threadIdx.x;
    const int lane = tid & 63;
    const int wid  = tid >> 6;
    const int wm = wid >> 1, wn = wid & 1;
    const int l15 = lane & 15, l4 = lane >> 4;
    const int brow = blockIdx.y * GBM;
    const int bcol = blockIdx.x * GBN;

    const int lhi  = lane >> 3;              // 0..7
    const int c8   = (lane & 7) ^ lhi;       // (g&7) == lhi for both chunks
    const int koff = (c8 & 3) * 8;           // element offset in k
    const int r0   = 32*wid + 2*lhi + (c8 >> 2);
    const int r1   = r0 + 16;
    const size_t a0 = (size_t)(brow + r0)*K + koff;
    const size_t a1 = (size_t)(brow + r1)*K + koff;
    const size_t b0 = (size_t)(bcol + r0)*K + koff;
    const size_t b1 = (size_t)(bcol + r1)*K + koff;
    char* lbase = (char*)&lds[0][0];
    const int cb0 = wid*2048, cb1 = wid*2048 + 1024;  // wave-uniform chunk bases

    const int ra = wm*64 + l15;
    const int ga = ra >> 1;
    const int abyte = ga*128 + (((((ra & 1) << 2) | l4) ^ (ga & 7)) << 4);
    const int rb = wn*64 + l15;
    const int gb = rb >> 1;
    const int bbyte = gb*128 + (((((rb & 1) << 2) | l4) ^ (gb & 7)) << 4);

    f32x4 acc[4][4] = {};

    for (int k0 = 0; k0 < K; k0 += GBK) {
        gload16(Ah  + a0 + k0, lbase         + cb0);
        gload16(Ah  + a1 + k0, lbase         + cb1);
        gload16(Al  + a0 + k0, lbase + 8192  + cb0);
        gload16(Al  + a1 + k0, lbase + 8192  + cb1);
        gload16(BhT + b0 + k0, lbase + 16384 + cb0);
        gload16(BhT + b1 + k0, lbase + 16384 + cb1);
        gload16(BlT + b0 + k0, lbase + 24576 + cb0);
        gload16(BlT + b1 + k0, lbase + 24576 + cb1);
        __syncthreads();

        short8 ah[4], al[4], bh[4], bl[4];
        #pragma unroll
        for (int m = 0; m < 4; ++m) {
            ah[m] = *(const short8*)(lbase         + abyte + m*1024);
            al[m] = *(const short8*)(lbase + 8192  + abyte + m*1024);
        }
        #pragma unroll
        for (int n = 0; n < 4; ++n) {
            bh[n] = *(const short8*)(lbase + 16384 + bbyte + n*1024);
            bl[n] = *(const short8*)(lbase + 24576 + bbyte + n*1024);
        }
        #pragma unroll
        for (int n = 0; n < 4; ++n)
            #pragma unroll
            for (int m = 0; m < 4; ++m) {
                acc[m][n] = __builtin_amdgcn_mfma_f32_16x16x32_bf16(ah[m], bh[n], acc[m][n], 0, 0, 0);
                acc[m][n] = __builtin_amdgcn_mfma_f32_16x16x32_bf16(ah[m], bl[n], acc[m][n], 0, 0, 0);
                acc[m][n] = __builtin_amdgcn_mfma_f32_16x16x32_bf16(al[m], bh[n], acc[m][n], 0, 0, 0);
            }
        __syncthreads();
    }

    #pragma unroll
    for (int n = 0; n < 4; ++n) {
        int col = bcol + wn*64 + n*16 + l15;
        float bv = bias[col];
        #pragma unroll
        for (int m = 0; m < 4; ++m) {
            int rbs = brow + wm*64 + m*16 + l4*4;
            #pragma unroll
            for (int r = 0; r < 4; ++r)
                C[(size_t)(rbs + r)*N + col] = acc[m][n][r] + bv;
        }
    }
}

// ---------------------------------------------------------------------------
// 3b) Fallback GEMM (in-kernel conversion, fp32 inputs) — Round-4 proven.
// ---------------------------------------------------------------------------
__global__ __launch_bounds__(256) void k_gemm_mfma(const float* __restrict__ A,
                                                   const float* __restrict__ B,
                                                   const float* __restrict__ bias,
                                                   float* __restrict__ C,
                                                   int M, int N, int K)
{
    __shared__ unsigned short As_hi[GBM][40];
    __shared__ unsigned short As_lo[GBM][40];
    __shared__ unsigned int   Bs[GBK][130];

    int tid  = threadIdx.x;
    int brow = blockIdx.y * GBM;
    int bcol = blockIdx.x * GBN;

    int lane = tid & 63;
    int wid  = tid >> 6;
    int wm   = wid >> 1;
    int wn   = wid & 1;
    int l15  = lane & 15;
    int l4   = lane >> 4;

    int a_m = tid >> 3;
    int a_c = tid & 7;
    int b_k = tid >> 5;
    int b_n = tid & 31;

    f32x4 acc[4][4] = {};

    for (int k0 = 0; k0 < K; k0 += GBK) {
        #pragma unroll
        for (int p = 0; p < 4; ++p) {
            int r = a_m + p*32;
            float4 v = *(const float4*)(A + (size_t)(brow + r)*K + k0 + a_c*4);
            unsigned h0 = pack_hi2(v.x, v.y);
            unsigned h1 = pack_hi2(v.z, v.w);
            float lx = v.x - hi_f32(v.x);
            float ly = v.y - hi_f32(v.y);
            float lz = v.z - hi_f32(v.z);
            float lw = v.w - hi_f32(v.w);
            unsigned l0 = pack_hi2(lx, ly);
            unsigned l1 = pack_hi2(lz, lw);
            *(uint2*)&As_hi[r][a_c*4] = make_uint2(h0, h1);
            *(uint2*)&As_lo[r][a_c*4] = make_uint2(l0, l1);
        }
        #pragma unroll
        for (int p = 0; p < 4; ++p) {
            int kk = b_k + p*8;
            float4 v = *(const float4*)(B + (size_t)(k0 + kk)*N + bcol + b_n*4);
            unsigned w0 = pack_pair(v.x);
            unsigned w1 = pack_pair(v.y);
            unsigned w2 = pack_pair(v.z);
            unsigned w3 = pack_pair(v.w);
            *(uint2*)&Bs[kk][b_n*4]     = make_uint2(w0, w1);
            *(uint2*)&Bs[kk][b_n*4 + 2] = make_uint2(w2, w3);
        }
        __syncthreads();

        short8 ah[4], al[4];
        #pragma unroll
        for (int m = 0; m < 4; ++m) {
            int r = wm*64 + m*16 + l15;
            ah[m] = *(const short8*)&As_hi[r][l4*8];
            al[m] = *(const short8*)&As_lo[r][l4*8];
        }

        #pragma unroll
        for (int n = 0; n < 4; ++n) {
            int col = wn*64 + n*16 + l15;
            unsigned w[8];
            #pragma unroll
            for (int j = 0; j < 8; ++j)
                w[j] = Bs[l4*8 + j][col];
            union { short8 v; unsigned d[4]; } bh, bl;
            #pragma unroll
            for (int d = 0; d < 4; ++d) {
                bh.d[d] = (w[2*d] >> 16)      | (w[2*d+1] & 0xFFFF0000u);
                bl.d[d] = (w[2*d] & 0xFFFFu)  | (w[2*d+1] << 16);
            }
            #pragma unroll
            for (int m = 0; m < 4; ++m) {
                acc[m][n] = __builtin_amdgcn_mfma_f32_16x16x32_bf16(ah[m], bh.v, acc[m][n], 0, 0, 0);
                acc[m][n] = __builtin_amdgcn_mfma_f32_16x16x32_bf16(ah[m], bl.v, acc[m][n], 0, 0, 0);
                acc[m][n] = __builtin_amdgcn_mfma_f32_16x16x32_bf16(al[m], bh.v, acc[m][n], 0, 0, 0);
            }
        }
        __syncthreads();
    }

    #pragma unroll
    for (int n = 0; n < 4; ++n) {
        int col = bcol + wn*64 + n*16 + l15;
        float bv = bias[col];
        #pragma unroll
        for (int m = 0; m < 4; ++m) {
            int rb = brow + wm*64 + m*16 + l4*4;
            #pragma unroll
            for (int r = 0; r < 4; ++r)
                C[(size_t)(rb + r)*N + col] = acc[m][n][r] + bv;
        }
    }
}

// ---------------------------------------------------------------------------
// 4) One LSTM timestep, v4: h4-reuse wave decomposition.
//    Grid: 256 blocks x 1024 thr (16 waves, 4/SIMD). Block owns 4 hidden
//    cols. Wave = (gate, K-quarter): covers ALL 4 cols over a 256-elem
//    K-slice, so each h4 LDS read feeds 4 cols (4x less LDS traffic than v3:
//    128KB vs 512KB per block-step). acc[4][8] partials -> 6-stage butterfly
//    (quarter sums in every lane) -> lane0 writes 8 float4 -> 32-thread tail
//    sums 4 quarters + activations. Race-free: reads hs[t-1], writes hs[t].
// ---------------------------------------------------------------------------
__global__ __launch_bounds__(1024) void k_lstm_step(const float* __restrict__ xg,
                                                    const float* __restrict__ WT,
                                                    float* __restrict__ c_state,
                                                    float* __restrict__ hs,
                                                    int t)
{
    __shared__ float h_lds[BATCH*HID];       // 32 KB: h rows [b][k]
    __shared__ float g_sm[4][4][4][8];       // [gate][kq][col][batch] = 2 KB

    const int tid  = threadIdx.x;
    const int wave = tid >> 6;               // 0..15
    const int lane = tid & 63;
    const int gate = wave >> 2;              // 0..3
    const int kq   = wave & 3;               // 0..3 K-quarter
    const int j0   = blockIdx.x * 4;

    float acc[4][8] = {};
    if (t > 0) {
        // stage h(t-1): 8 rows x 256 float4; 1024 thr -> 2 float4 each
        {
            int b   = tid >> 7;              // 0..7
            int off = tid & 127;
            const float4* src = (const float4*)(hs + ((size_t)b*SEQ + (t-1))*HID);
            float4* dst = (float4*)(h_lds + b*HID);
            dst[off]       = src[off];
            dst[off + 128] = src[off + 128];
        }
        __syncthreads();

        const int k4 = kq*64 + lane;         // float4 index in [0,256)
        float4 w4[4];
        #pragma unroll
        for (int jl = 0; jl < 4; ++jl)
            w4[jl] = ((const float4*)(WT + (size_t)(gate*HID + j0 + jl)*HID))[k4];

        #pragma unroll
        for (int b = 0; b < 8; ++b) {
            float4 h4 = ((const float4*)(h_lds + b*HID))[k4];   // reused x4 cols
            #pragma unroll
            for (int jl = 0; jl < 4; ++jl)
                acc[jl][b] += w4[jl].x*h4.x + w4[jl].y*h4.y
                            + w4[jl].z*h4.z + w4[jl].w*h4.w;
        }

        #pragma unroll
        for (int jl = 0; jl < 4; ++jl)
            #pragma unroll
            for (int b = 0; b < 8; ++b) {
                float v = acc[jl][b];
                v += __shfl_xor(v, 32);
                v += __shfl_xor(v, 16);
                v += __shfl_xor(v, 8);
                v += __shfl_xor(v, 4);
                v += __shfl_xor(v, 2);
                v += __shfl_xor(v, 1);
                acc[jl][b] = v;
            }
    }

    if (lane == 0) {
        #pragma unroll
        for (int jl = 0; jl < 4; ++jl) {
            *(float4*)&g_sm[gate][kq][jl][0] =
                make_float4(acc[jl][0], acc[jl][1], acc[jl][2], acc[jl][3]);
            *(float4*)&g_sm[gate][kq][jl][4] =
                make_float4(acc[jl][4], acc[jl][5], acc[jl][6], acc[jl][7]);
        }
    }
    __syncthreads();

    if (tid < 32) {
        int b  = tid & 7;
        int jj = tid >> 3;                   // 0..3
        int jc = j0 + jj;
        size_t xbase = ((size_t)b*SEQ + t)*GD + jc;
        float iv = g_sm[0][0][jj][b] + g_sm[0][1][jj][b]
                 + g_sm[0][2][jj][b] + g_sm[0][3][jj][b] + xg[xbase];
        float fv = g_sm[1][0][jj][b] + g_sm[1][1][jj][b]
                 + g_sm[1][2][jj][b] + g_sm[1][3][jj][b] + xg[xbase + HID];
        float gv = g_sm[2][0][jj][b] + g_sm[2][1][jj][b]
                 + g_sm[2][2][jj][b] + g_sm[2][3][jj][b] + xg[xbase + 2*HID];
        float ov = g_sm[3][0][jj][b] + g_sm[3][1][jj][b]
                 + g_sm[3][2][jj][b] + g_sm[3][3][jj][b] + xg[xbase + 3*HID];
        iv = 1.0f / (1.0f + expf(-iv));
        fv = 1.0f / (1.0f + expf(-fv));
        gv = tanhf(gv);
        ov = 1.0f / (1.0f + expf(-ov));
        float c  = (t > 0) ? c_state[(size_t)b*HID + jc] : 0.0f;
        float cn = fv*c + iv*gv;
        float hn = ov * tanhf(cn);
        c_state[(size_t)b*HID + jc] = cn;
        hs[((size_t)b*SEQ + t)*HID + jc] = hn;
    }
}

// ---------------------------------------------------------------------------
// Launch
// ---------------------------------------------------------------------------
extern "C" void kernel_launch(void* const* d_in, const int* in_sizes, int n_in,
                              void* d_out, int out_size, void* d_ws, size_t ws_size,
                              hipStream_t stream)
{
    const int*   ids    = (const int*)  d_in[0];
    const float* w_out  = (const float*)d_in[1];
    const float* b_out  = (const float*)d_in[2];
    const float* W_ih   = (const float*)d_in[3];
    const float* W_hh   = (const float*)d_in[4];
    const float* b_lstm = (const float*)d_in[5];
    float* out = (float*)d_out;

    // d_out scratch (524 MB): every region dead before the final GEMM writes C.
    char* ob = (char*)d_out;
    unsigned short* emb_hi  = (unsigned short*)(ob);               //  8,388,608 B
    unsigned short* emb_lo  = (unsigned short*)(ob + 8388608);     //  8,388,608 B
    float*          WT      = (float*)(ob + 16777216);             // 16,777,216 B
    float*          xg      = (float*)(ob + 33554432);             // 67,108,864 B
    float*          cstate  = (float*)(ob + 100663296);            //     32,768 B
    unsigned short* wih_hiT = (unsigned short*)(ob + 100696064);   //  8,388,608 B
    unsigned short* wih_loT = (unsigned short*)(ob + 109084672);   //  8,388,608 B
    float*          hs_dout = (float*)(ob + 117473280);            // 16,777,216 B

    // d_ws: fast path needs hs_hi/lo + w_out^T hi/lo = 147,849,216 B.
    char* wb = (char*)d_ws;
    const size_t NEED = 147849216ull;
    const bool big_ws = (ws_size >= NEED);
    unsigned short* hs_hi  = (unsigned short*)(wb);                //  8,388,608 B
    unsigned short* hs_lo  = (unsigned short*)(wb + 8388608);      //  8,388,608 B
    unsigned short* wo_hiT = (unsigned short*)(wb + 16777216);     // 65,536,000 B
    unsigned short* wo_loT = (unsigned short*)(wb + 82313216);     // 65,536,000 B
    float* hs = big_ws ? hs_dout : (float*)wb;

    // 1) embedding gather (split to hi/lo bf16)
    k_gather_split<<<ROWS, 256, 0, stream>>>(ids, w_out, emb_hi, emb_lo);

    // 2) transpose W_hh (fp32) for the scan
    k_transpose<<<dim3(GD/32, HID/32), dim3(32, 8), 0, stream>>>(W_hh, WT);

    // 2b) W_ih -> transposed hi/lo bf16 [GD][HID]
    k_transsplit<<<dim3(GD/32, HID/32), dim3(32, 8), 0, stream>>>(
        W_ih, wih_hiT, wih_loT, GD);

    // 3) x_gates = emb @ W_ih + b_lstm  (K-major fast MFMA GEMM)
    k_gemm_fast<<<dim3(GD/GBN, ROWS/GBM), 256, 0, stream>>>(
        emb_hi, emb_lo, wih_hiT, wih_loT, b_lstm, xg, ROWS, GD, HID);

    // 4) sequential LSTM scan: 512 launches (launch boundary = HW grid barrier)
    for (int t = 0; t < SEQ; ++t)
        k_lstm_step<<<HID/4, 1024, 0, stream>>>(xg, WT, cstate, hs, t);

    // 5) logits = hs @ w_out + b_out
    if (big_ws) {
        k_transsplit<<<dim3(VOCAB/32, HID/32), dim3(32, 8), 0, stream>>>(
            w_out, wo_hiT, wo_loT, VOCAB);
        k_split_f32<<<1024, 256, 0, stream>>>(hs, hs_hi, hs_lo, (long)ROWS*HID/4);
        k_gemm_fast<<<dim3(VOCAB/GBN, ROWS/GBM), 256, 0, stream>>>(
            hs_hi, hs_lo, wo_hiT, wo_loT, b_out, out, ROWS, VOCAB, HID);
    } else {
        k_gemm_mfma<<<dim3(VOCAB/GBN, ROWS/GBM), 256, 0, stream>>>(
            hs, w_out, b_out, out, ROWS, VOCAB, HID);
    }
}

// Round 11
// 4760.260 us; speedup vs baseline: 1.5946x; 1.5946x over previous
//
#include <hip/hip_runtime.h>
#include <math.h>

#define VOCAB 32000
#define HID   1024
#define BATCH 8
#define SEQ   512
#define GD    (4*HID)       // 4096 gate width
#define ROWS  (BATCH*SEQ)   // 4096

typedef __attribute__((ext_vector_type(8))) short short8;
typedef __attribute__((ext_vector_type(4))) float f32x4;

__device__ __forceinline__ float hi_f32(float x) {
    return __uint_as_float(__float_as_uint(x) & 0xFFFF0000u);
}
// packed word: hi bf16 bits in high half, lo bf16 bits in low half
__device__ __forceinline__ unsigned pack_pair(float x) {
    unsigned hb = __float_as_uint(x) & 0xFFFF0000u;
    float lo = x - __uint_as_float(hb);
    return hb | (__float_as_uint(lo) >> 16);
}
__device__ __forceinline__ unsigned pack_hi2(float x, float y) {
    return (__float_as_uint(x) >> 16) | (__float_as_uint(y) & 0xFFFF0000u);
}

// async 16B/lane global->LDS (dest = wave-uniform base + lane*16)
__device__ __forceinline__ void gload16(const void* g, void* l) {
    __builtin_amdgcn_global_load_lds(
        (__attribute__((address_space(1))) void*)g,
        (__attribute__((address_space(3))) void*)l, 16, 0, 0);
}

// ---------------------------------------------------------------------------
// 1) Embedding gather, split: emb_hi/lo[row][h] = split(w_out[h][ids[row]])
// ---------------------------------------------------------------------------
__global__ __launch_bounds__(256) void k_gather_split(const int* __restrict__ ids,
                                                      const float* __restrict__ w_out,
                                                      unsigned short* __restrict__ emb_hi,
                                                      unsigned short* __restrict__ emb_lo)
{
    int row = blockIdx.x;            // 0..4095
    int id  = ids[row];
    const float* src = w_out + id;   // column id, stride VOCAB
    for (int h = threadIdx.x; h < HID; h += 256) {
        float v  = src[(size_t)h * VOCAB];
        float lo = v - hi_f32(v);
        emb_hi[(size_t)row*HID + h] = (unsigned short)(__float_as_uint(v)  >> 16);
        emb_lo[(size_t)row*HID + h] = (unsigned short)(__float_as_uint(lo) >> 16);
    }
}

// ---------------------------------------------------------------------------
// 2) Transpose W_hh [1024][4096] -> W_hhT [4096][1024] (fp32, for the scan)
// ---------------------------------------------------------------------------
__global__ __launch_bounds__(256) void k_transpose(const float* __restrict__ W,
                                                   float* __restrict__ WT)
{
    __shared__ float tile[32][33];
    int tx = threadIdx.x, ty = threadIdx.y;
    int x = blockIdx.x*32 + tx;
    int y = blockIdx.y*32 + ty;
    #pragma unroll
    for (int i = 0; i < 32; i += 8)
        tile[ty + i][tx] = W[(size_t)(y + i)*GD + x];
    __syncthreads();
    int k   = blockIdx.y*32 + tx;
    int col = blockIdx.x*32 + ty;
    #pragma unroll
    for (int i = 0; i < 32; i += 8)
        WT[(size_t)(col + i)*HID + k] = tile[tx][ty + i];
}

// ---------------------------------------------------------------------------
// 2b) Transpose + split: W[K=1024][N] f32 -> hiT/loT[N][1024] bf16 bits
// ---------------------------------------------------------------------------
__global__ __launch_bounds__(256) void k_transsplit(const float* __restrict__ W,
                                                    unsigned short* __restrict__ hiT,
                                                    unsigned short* __restrict__ loT,
                                                    int N)
{
    __shared__ float tile[32][33];
    int tx = threadIdx.x, ty = threadIdx.y;
    int x = blockIdx.x*32 + tx;      // N
    int y = blockIdx.y*32 + ty;      // K
    #pragma unroll
    for (int i = 0; i < 32; i += 8)
        tile[ty + i][tx] = W[(size_t)(y + i)*N + x];
    __syncthreads();
    int n = blockIdx.x*32 + ty;
    int k = blockIdx.y*32 + tx;
    #pragma unroll
    for (int i = 0; i < 32; i += 8) {
        float v  = tile[tx][ty + i];
        float lo = v - hi_f32(v);
        hiT[(size_t)(n + i)*HID + k] = (unsigned short)(__float_as_uint(v)  >> 16);
        loT[(size_t)(n + i)*HID + k] = (unsigned short)(__float_as_uint(lo) >> 16);
    }
}

// ---------------------------------------------------------------------------
// 2c) Split fp32 -> hi bf16, lo bf16 arrays (grid-stride, float4)
// ---------------------------------------------------------------------------
__global__ __launch_bounds__(256) void k_split_f32(const float* __restrict__ src,
                                                   unsigned short* __restrict__ hi,
                                                   unsigned short* __restrict__ lo,
                                                   long n4)
{
    long i0 = (long)blockIdx.x * 256 + threadIdx.x;
    long stride = (long)gridDim.x * 256;
    for (long i = i0; i < n4; i += stride) {
        float4 v = ((const float4*)src)[i];
        unsigned h0 = __float_as_uint(v.x) >> 16, h1 = __float_as_uint(v.y) >> 16;
        unsigned h2 = __float_as_uint(v.z) >> 16, h3 = __float_as_uint(v.w) >> 16;
        unsigned l0 = __float_as_uint(v.x - hi_f32(v.x)) >> 16;
        unsigned l1 = __float_as_uint(v.y - hi_f32(v.y)) >> 16;
        unsigned l2 = __float_as_uint(v.z - hi_f32(v.z)) >> 16;
        unsigned l3 = __float_as_uint(v.w - hi_f32(v.w)) >> 16;
        ((uint2*)hi)[i] = make_uint2(h0 | (h1 << 16), h2 | (h3 << 16));
        ((uint2*)lo)[i] = make_uint2(l0 | (l1 << 16), l2 | (l3 << 16));
    }
}

// ---------------------------------------------------------------------------
// 3) Fast split-bf16 MFMA GEMM, all operands K-major bf16 bits (R8 proven).
// ---------------------------------------------------------------------------
#define GBM 128
#define GBN 128
#define GBK 32

__global__ __launch_bounds__(256) void k_gemm_fast(
    const unsigned short* __restrict__ Ah,  const unsigned short* __restrict__ Al,
    const unsigned short* __restrict__ BhT, const unsigned short* __restrict__ BlT,
    const float* __restrict__ bias, float* __restrict__ C,
    int M, int N, int K)
{
    __shared__ __align__(16) unsigned short lds[4][4096];  // Ah,Al,Bh,Bl: 8KB each

    const int tid  = threadIdx.x;
    const int lane = tid & 63;
    const int wid  = tid >> 6;
    const int wm = wid >> 1, wn = wid & 1;
    const int l15 = lane & 15, l4 = lane >> 4;
    const int brow = blockIdx.y * GBM;
    const int bcol = blockIdx.x * GBN;

    const int lhi  = lane >> 3;              // 0..7
    const int c8   = (lane & 7) ^ lhi;       // (g&7) == lhi for both chunks
    const int koff = (c8 & 3) * 8;           // element offset in k
    const int r0   = 32*wid + 2*lhi + (c8 >> 2);
    const int r1   = r0 + 16;
    const size_t a0 = (size_t)(brow + r0)*K + koff;
    const size_t a1 = (size_t)(brow + r1)*K + koff;
    const size_t b0 = (size_t)(bcol + r0)*K + koff;
    const size_t b1 = (size_t)(bcol + r1)*K + koff;
    char* lbase = (char*)&lds[0][0];
    const int cb0 = wid*2048, cb1 = wid*2048 + 1024;  // wave-uniform chunk bases

    const int ra = wm*64 + l15;
    const int ga = ra >> 1;
    const int abyte = ga*128 + (((((ra & 1) << 2) | l4) ^ (ga & 7)) << 4);
    const int rb = wn*64 + l15;
    const int gb = rb >> 1;
    const int bbyte = gb*128 + (((((rb & 1) << 2) | l4) ^ (gb & 7)) << 4);

    f32x4 acc[4][4] = {};

    for (int k0 = 0; k0 < K; k0 += GBK) {
        gload16(Ah  + a0 + k0, lbase         + cb0);
        gload16(Ah  + a1 + k0, lbase         + cb1);
        gload16(Al  + a0 + k0, lbase + 8192  + cb0);
        gload16(Al  + a1 + k0, lbase + 8192  + cb1);
        gload16(BhT + b0 + k0, lbase + 16384 + cb0);
        gload16(BhT + b1 + k0, lbase + 16384 + cb1);
        gload16(BlT + b0 + k0, lbase + 24576 + cb0);
        gload16(BlT + b1 + k0, lbase + 24576 + cb1);
        __syncthreads();

        short8 ah[4], al[4], bh[4], bl[4];
        #pragma unroll
        for (int m = 0; m < 4; ++m) {
            ah[m] = *(const short8*)(lbase         + abyte + m*1024);
            al[m] = *(const short8*)(lbase + 8192  + abyte + m*1024);
        }
        #pragma unroll
        for (int n = 0; n < 4; ++n) {
            bh[n] = *(const short8*)(lbase + 16384 + bbyte + n*1024);
            bl[n] = *(const short8*)(lbase + 24576 + bbyte + n*1024);
        }
        #pragma unroll
        for (int n = 0; n < 4; ++n)
            #pragma unroll
            for (int m = 0; m < 4; ++m) {
                acc[m][n] = __builtin_amdgcn_mfma_f32_16x16x32_bf16(ah[m], bh[n], acc[m][n], 0, 0, 0);
                acc[m][n] = __builtin_amdgcn_mfma_f32_16x16x32_bf16(ah[m], bl[n], acc[m][n], 0, 0, 0);
                acc[m][n] = __builtin_amdgcn_mfma_f32_16x16x32_bf16(al[m], bh[n], acc[m][n], 0, 0, 0);
            }
        __syncthreads();
    }

    #pragma unroll
    for (int n = 0; n < 4; ++n) {
        int col = bcol + wn*64 + n*16 + l15;
        float bv = bias[col];
        #pragma unroll
        for (int m = 0; m < 4; ++m) {
            int rbs = brow + wm*64 + m*16 + l4*4;
            #pragma unroll
            for (int r = 0; r < 4; ++r)
                C[(size_t)(rbs + r)*N + col] = acc[m][n][r] + bv;
        }
    }
}

// ---------------------------------------------------------------------------
// 3b) Fallback GEMM (in-kernel conversion, fp32 inputs) — Round-4 proven.
// ---------------------------------------------------------------------------
__global__ __launch_bounds__(256) void k_gemm_mfma(const float* __restrict__ A,
                                                   const float* __restrict__ B,
                                                   const float* __restrict__ bias,
                                                   float* __restrict__ C,
                                                   int M, int N, int K)
{
    __shared__ unsigned short As_hi[GBM][40];
    __shared__ unsigned short As_lo[GBM][40];
    __shared__ unsigned int   Bs[GBK][130];

    int tid  = threadIdx.x;
    int brow = blockIdx.y * GBM;
    int bcol = blockIdx.x * GBN;

    int lane = tid & 63;
    int wid  = tid >> 6;
    int wm   = wid >> 1;
    int wn   = wid & 1;
    int l15  = lane & 15;
    int l4   = lane >> 4;

    int a_m = tid >> 3;
    int a_c = tid & 7;
    int b_k = tid >> 5;
    int b_n = tid & 31;

    f32x4 acc[4][4] = {};

    for (int k0 = 0; k0 < K; k0 += GBK) {
        #pragma unroll
        for (int p = 0; p < 4; ++p) {
            int r = a_m + p*32;
            float4 v = *(const float4*)(A + (size_t)(brow + r)*K + k0 + a_c*4);
            unsigned h0 = pack_hi2(v.x, v.y);
            unsigned h1 = pack_hi2(v.z, v.w);
            float lx = v.x - hi_f32(v.x);
            float ly = v.y - hi_f32(v.y);
            float lz = v.z - hi_f32(v.z);
            float lw = v.w - hi_f32(v.w);
            unsigned l0 = pack_hi2(lx, ly);
            unsigned l1 = pack_hi2(lz, lw);
            *(uint2*)&As_hi[r][a_c*4] = make_uint2(h0, h1);
            *(uint2*)&As_lo[r][a_c*4] = make_uint2(l0, l1);
        }
        #pragma unroll
        for (int p = 0; p < 4; ++p) {
            int kk = b_k + p*8;
            float4 v = *(const float4*)(B + (size_t)(k0 + kk)*N + bcol + b_n*4);
            unsigned w0 = pack_pair(v.x);
            unsigned w1 = pack_pair(v.y);
            unsigned w2 = pack_pair(v.z);
            unsigned w3 = pack_pair(v.w);
            *(uint2*)&Bs[kk][b_n*4]     = make_uint2(w0, w1);
            *(uint2*)&Bs[kk][b_n*4 + 2] = make_uint2(w2, w3);
        }
        __syncthreads();

        short8 ah[4], al[4];
        #pragma unroll
        for (int m = 0; m < 4; ++m) {
            int r = wm*64 + m*16 + l15;
            ah[m] = *(const short8*)&As_hi[r][l4*8];
            al[m] = *(const short8*)&As_lo[r][l4*8];
        }

        #pragma unroll
        for (int n = 0; n < 4; ++n) {
            int col = wn*64 + n*16 + l15;
            unsigned w[8];
            #pragma unroll
            for (int j = 0; j < 8; ++j)
                w[j] = Bs[l4*8 + j][col];
            union { short8 v; unsigned d[4]; } bh, bl;
            #pragma unroll
            for (int d = 0; d < 4; ++d) {
                bh.d[d] = (w[2*d] >> 16)      | (w[2*d+1] & 0xFFFF0000u);
                bl.d[d] = (w[2*d] & 0xFFFFu)  | (w[2*d+1] << 16);
            }
            #pragma unroll
            for (int m = 0; m < 4; ++m) {
                acc[m][n] = __builtin_amdgcn_mfma_f32_16x16x32_bf16(ah[m], bh.v, acc[m][n], 0, 0, 0);
                acc[m][n] = __builtin_amdgcn_mfma_f32_16x16x32_bf16(ah[m], bl.v, acc[m][n], 0, 0, 0);
                acc[m][n] = __builtin_amdgcn_mfma_f32_16x16x32_bf16(al[m], bh.v, acc[m][n], 0, 0, 0);
            }
        }
        __syncthreads();
    }

    #pragma unroll
    for (int n = 0; n < 4; ++n) {
        int col = bcol + wn*64 + n*16 + l15;
        float bv = bias[col];
        #pragma unroll
        for (int m = 0; m < 4; ++m) {
            int rb = brow + wm*64 + m*16 + l4*4;
            #pragma unroll
            for (int r = 0; r < 4; ++r)
                C[(size_t)(rb + r)*N + col] = acc[m][n][r] + bv;
        }
    }
}

// ---------------------------------------------------------------------------
// 4) One LSTM timestep, v5: v3 structure (acc[8], 48 shfl — proven) with
//    (a) tail-operand prefetch: xg/c_state loads issued at kernel start,
//        consumed after the barrier -> latency hidden under the matvec;
//    (b) 512 blocks x 512 thr (block = 2 cols, 8 waves = 4 gates x 2 cols,
//        2 blocks/CU): a co-resident block's matvec overlaps this block's
//        barrier + 16-thread tail.
//    Per-wave K-partition, FMA order, butterfly identical to v3 ->
//    bitwise-identical results. Race-free: reads hs[t-1], writes hs[t].
// ---------------------------------------------------------------------------
#define SCB 2              // cols per scan block

__global__ __launch_bounds__(512) void k_lstm_step(const float* __restrict__ xg,
                                                   const float* __restrict__ WT,
                                                   float* __restrict__ c_state,
                                                   float* __restrict__ hs,
                                                   int t)
{
    __shared__ float h_lds[BATCH*HID];    // 32 KB: h rows [b][k]
    __shared__ float g_sm[4][SCB][8];     // [gate][col][batch]

    const int tid  = threadIdx.x;
    const int wave = tid >> 6;            // 0..7
    const int lane = tid & 63;
    const int gate = wave >> 1;           // 0..3
    const int jl   = wave & 1;            // 0..1
    const int j0   = blockIdx.x * SCB;
    const int col  = gate*HID + (j0 + jl);

    // (a) prefetch tail operands early (used only after the barrier)
    float xv0 = 0, xv1 = 0, xv2 = 0, xv3 = 0, cv = 0;
    const int tb = tid & 7;               // batch   (tail thread)
    const int tj = (tid >> 3) & (SCB-1);  // col idx (tail thread)
    if (tid < 8*SCB) {
        int jc = j0 + tj;
        size_t xbase = ((size_t)tb*SEQ + t)*GD + jc;
        xv0 = xg[xbase];
        xv1 = xg[xbase + HID];
        xv2 = xg[xbase + 2*HID];
        xv3 = xg[xbase + 3*HID];
        cv  = (t > 0) ? c_state[(size_t)tb*HID + jc] : 0.0f;
    }

    float acc[8] = {};
    if (t > 0) {
        // stage h(t-1): 8 rows x 256 float4; 512 thr -> 4 float4 each
        {
            int b   = tid >> 6;           // 0..7
            int off = tid & 63;
            const float4* src = (const float4*)(hs + ((size_t)b*SEQ + (t-1))*HID);
            float4* dst = (float4*)(h_lds + b*HID);
            dst[off      ] = src[off      ];
            dst[off +  64] = src[off +  64];
            dst[off + 128] = src[off + 128];
            dst[off + 192] = src[off + 192];
        }
        __syncthreads();

        const float4* wv = (const float4*)(WT + (size_t)col*HID);
        #pragma unroll
        for (int c = 0; c < 4; ++c) {
            int k4 = c*64 + lane;
            float4 w4 = wv[k4];
            #pragma unroll
            for (int b = 0; b < 8; ++b) {
                float4 h4 = ((const float4*)(h_lds + b*HID))[k4];
                acc[b] += w4.x*h4.x + w4.y*h4.y + w4.z*h4.z + w4.w*h4.w;
            }
        }
        #pragma unroll
        for (int b = 0; b < 8; ++b) {
            acc[b] += __shfl_xor(acc[b], 32);
            acc[b] += __shfl_xor(acc[b], 16);
            acc[b] += __shfl_xor(acc[b], 8);
            acc[b] += __shfl_xor(acc[b], 4);
            acc[b] += __shfl_xor(acc[b], 2);
            acc[b] += __shfl_xor(acc[b], 1);
        }
    }

    if (lane == 0) {
        #pragma unroll
        for (int b = 0; b < 8; ++b)
            g_sm[gate][jl][b] = acc[b];
    }
    __syncthreads();

    if (tid < 8*SCB) {
        int jc = j0 + tj;
        float iv = g_sm[0][tj][tb] + xv0;
        float fv = g_sm[1][tj][tb] + xv1;
        float gv = g_sm[2][tj][tb] + xv2;
        float ov = g_sm[3][tj][tb] + xv3;
        iv = 1.0f / (1.0f + expf(-iv));
        fv = 1.0f / (1.0f + expf(-fv));
        gv = tanhf(gv);
        ov = 1.0f / (1.0f + expf(-ov));
        float cn = fv*cv + iv*gv;
        float hn = ov * tanhf(cn);
        c_state[(size_t)tb*HID + jc] = cn;
        hs[((size_t)tb*SEQ + t)*HID + jc] = hn;
    }
}

// ---------------------------------------------------------------------------
// Launch
// ---------------------------------------------------------------------------
extern "C" void kernel_launch(void* const* d_in, const int* in_sizes, int n_in,
                              void* d_out, int out_size, void* d_ws, size_t ws_size,
                              hipStream_t stream)
{
    const int*   ids    = (const int*)  d_in[0];
    const float* w_out  = (const float*)d_in[1];
    const float* b_out  = (const float*)d_in[2];
    const float* W_ih   = (const float*)d_in[3];
    const float* W_hh   = (const float*)d_in[4];
    const float* b_lstm = (const float*)d_in[5];
    float* out = (float*)d_out;

    // d_out scratch (524 MB): every region dead before the final GEMM writes C.
    char* ob = (char*)d_out;
    unsigned short* emb_hi  = (unsigned short*)(ob);               //  8,388,608 B
    unsigned short* emb_lo  = (unsigned short*)(ob + 8388608);     //  8,388,608 B
    float*          WT      = (float*)(ob + 16777216);             // 16,777,216 B
    float*          xg      = (float*)(ob + 33554432);             // 67,108,864 B
    float*          cstate  = (float*)(ob + 100663296);            //     32,768 B
    unsigned short* wih_hiT = (unsigned short*)(ob + 100696064);   //  8,388,608 B
    unsigned short* wih_loT = (unsigned short*)(ob + 109084672);   //  8,388,608 B
    float*          hs_dout = (float*)(ob + 117473280);            // 16,777,216 B

    // d_ws: fast path needs hs_hi/lo + w_out^T hi/lo = 147,849,216 B.
    char* wb = (char*)d_ws;
    const size_t NEED = 147849216ull;
    const bool big_ws = (ws_size >= NEED);
    unsigned short* hs_hi  = (unsigned short*)(wb);                //  8,388,608 B
    unsigned short* hs_lo  = (unsigned short*)(wb + 8388608);      //  8,388,608 B
    unsigned short* wo_hiT = (unsigned short*)(wb + 16777216);     // 65,536,000 B
    unsigned short* wo_loT = (unsigned short*)(wb + 82313216);     // 65,536,000 B
    float* hs = big_ws ? hs_dout : (float*)wb;

    // 1) embedding gather (split to hi/lo bf16)
    k_gather_split<<<ROWS, 256, 0, stream>>>(ids, w_out, emb_hi, emb_lo);

    // 2) transpose W_hh (fp32) for the scan
    k_transpose<<<dim3(GD/32, HID/32), dim3(32, 8), 0, stream>>>(W_hh, WT);

    // 2b) W_ih -> transposed hi/lo bf16 [GD][HID]
    k_transsplit<<<dim3(GD/32, HID/32), dim3(32, 8), 0, stream>>>(
        W_ih, wih_hiT, wih_loT, GD);

    // 3) x_gates = emb @ W_ih + b_lstm  (K-major fast MFMA GEMM)
    k_gemm_fast<<<dim3(GD/GBN, ROWS/GBM), 256, 0, stream>>>(
        emb_hi, emb_lo, wih_hiT, wih_loT, b_lstm, xg, ROWS, GD, HID);

    // 4) sequential LSTM scan: 512 launches (launch boundary = HW grid barrier)
    for (int t = 0; t < SEQ; ++t)
        k_lstm_step<<<HID/SCB, 512, 0, stream>>>(xg, WT, cstate, hs, t);

    // 5) logits = hs @ w_out + b_out
    if (big_ws) {
        k_transsplit<<<dim3(VOCAB/32, HID/32), dim3(32, 8), 0, stream>>>(
            w_out, wo_hiT, wo_loT, VOCAB);
        k_split_f32<<<1024, 256, 0, stream>>>(hs, hs_hi, hs_lo, (long)ROWS*HID/4);
        k_gemm_fast<<<dim3(VOCAB/GBN, ROWS/GBM), 256, 0, stream>>>(
            hs_hi, hs_lo, wo_hiT, wo_loT, b_out, out, ROWS, VOCAB, HID);
    } else {
        k_gemm_mfma<<<dim3(VOCAB/GBN, ROWS/GBM), 256, 0, stream>>>(
            hs, w_out, b_out, out, ROWS, VOCAB, HID);
    }
}

// Round 12
// 4671.387 us; speedup vs baseline: 1.6249x; 1.0190x over previous
//
#include <hip/hip_runtime.h>
#include <math.h>

#define VOCAB 32000
#define HID   1024
#define BATCH 8
#define SEQ   512
#define GD    (4*HID)       // 4096 gate width
#define ROWS  (BATCH*SEQ)   // 4096

typedef __attribute__((ext_vector_type(8))) short short8;
typedef __attribute__((ext_vector_type(4))) float f32x4;

__device__ __forceinline__ float hi_f32(float x) {
    return __uint_as_float(__float_as_uint(x) & 0xFFFF0000u);
}
// packed word: hi bf16 bits in high half, lo bf16 bits in low half
__device__ __forceinline__ unsigned pack_pair(float x) {
    unsigned hb = __float_as_uint(x) & 0xFFFF0000u;
    float lo = x - __uint_as_float(hb);
    return hb | (__float_as_uint(lo) >> 16);
}
__device__ __forceinline__ unsigned pack_hi2(float x, float y) {
    return (__float_as_uint(x) >> 16) | (__float_as_uint(y) & 0xFFFF0000u);
}

// async 16B/lane global->LDS (dest = wave-uniform base + lane*16)
__device__ __forceinline__ void gload16(const void* g, void* l) {
    __builtin_amdgcn_global_load_lds(
        (__attribute__((address_space(1))) void*)g,
        (__attribute__((address_space(3))) void*)l, 16, 0, 0);
}

// ---------------------------------------------------------------------------
// 1) Embedding gather, split: emb_hi/lo[row][h] = split(w_out[h][ids[row]])
// ---------------------------------------------------------------------------
__global__ __launch_bounds__(256) void k_gather_split(const int* __restrict__ ids,
                                                      const float* __restrict__ w_out,
                                                      unsigned short* __restrict__ emb_hi,
                                                      unsigned short* __restrict__ emb_lo)
{
    int row = blockIdx.x;            // 0..4095
    int id  = ids[row];
    const float* src = w_out + id;   // column id, stride VOCAB
    for (int h = threadIdx.x; h < HID; h += 256) {
        float v  = src[(size_t)h * VOCAB];
        float lo = v - hi_f32(v);
        emb_hi[(size_t)row*HID + h] = (unsigned short)(__float_as_uint(v)  >> 16);
        emb_lo[(size_t)row*HID + h] = (unsigned short)(__float_as_uint(lo) >> 16);
    }
}

// ---------------------------------------------------------------------------
// 2) Transpose + split: W[K=1024][N] f32 -> hiT/loT[N][1024] bf16 bits
// ---------------------------------------------------------------------------
__global__ __launch_bounds__(256) void k_transsplit(const float* __restrict__ W,
                                                    unsigned short* __restrict__ hiT,
                                                    unsigned short* __restrict__ loT,
                                                    int N)
{
    __shared__ float tile[32][33];
    int tx = threadIdx.x, ty = threadIdx.y;
    int x = blockIdx.x*32 + tx;      // N
    int y = blockIdx.y*32 + ty;      // K
    #pragma unroll
    for (int i = 0; i < 32; i += 8)
        tile[ty + i][tx] = W[(size_t)(y + i)*N + x];
    __syncthreads();
    int n = blockIdx.x*32 + ty;
    int k = blockIdx.y*32 + tx;
    #pragma unroll
    for (int i = 0; i < 32; i += 8) {
        float v  = tile[tx][ty + i];
        float lo = v - hi_f32(v);
        hiT[(size_t)(n + i)*HID + k] = (unsigned short)(__float_as_uint(v)  >> 16);
        loT[(size_t)(n + i)*HID + k] = (unsigned short)(__float_as_uint(lo) >> 16);
    }
}

// ---------------------------------------------------------------------------
// 2c) Split fp32 -> hi bf16, lo bf16 arrays (grid-stride, float4)
// ---------------------------------------------------------------------------
__global__ __launch_bounds__(256) void k_split_f32(const float* __restrict__ src,
                                                   unsigned short* __restrict__ hi,
                                                   unsigned short* __restrict__ lo,
                                                   long n4)
{
    long i0 = (long)blockIdx.x * 256 + threadIdx.x;
    long stride = (long)gridDim.x * 256;
    for (long i = i0; i < n4; i += stride) {
        float4 v = ((const float4*)src)[i];
        unsigned h0 = __float_as_uint(v.x) >> 16, h1 = __float_as_uint(v.y) >> 16;
        unsigned h2 = __float_as_uint(v.z) >> 16, h3 = __float_as_uint(v.w) >> 16;
        unsigned l0 = __float_as_uint(v.x - hi_f32(v.x)) >> 16;
        unsigned l1 = __float_as_uint(v.y - hi_f32(v.y)) >> 16;
        unsigned l2 = __float_as_uint(v.z - hi_f32(v.z)) >> 16;
        unsigned l3 = __float_as_uint(v.w - hi_f32(v.w)) >> 16;
        ((uint2*)hi)[i] = make_uint2(h0 | (h1 << 16), h2 | (h3 << 16));
        ((uint2*)lo)[i] = make_uint2(l0 | (l1 << 16), l2 | (l3 << 16));
    }
}

// ---------------------------------------------------------------------------
// 2d) Zero helper (for the h ping-pong buffers; d_ws/d_out are 0xAA-poisoned)
// ---------------------------------------------------------------------------
__global__ __launch_bounds__(256) void k_zero16(uint4* __restrict__ p, long n16)
{
    long i = (long)blockIdx.x * 256 + threadIdx.x;
    if (i < n16) p[i] = make_uint4(0u, 0u, 0u, 0u);
}

// ---------------------------------------------------------------------------
// 3) Fast split-bf16 MFMA GEMM, all operands K-major bf16 bits (R8 proven).
// ---------------------------------------------------------------------------
#define GBM 128
#define GBN 128
#define GBK 32

__global__ __launch_bounds__(256) void k_gemm_fast(
    const unsigned short* __restrict__ Ah,  const unsigned short* __restrict__ Al,
    const unsigned short* __restrict__ BhT, const unsigned short* __restrict__ BlT,
    const float* __restrict__ bias, float* __restrict__ C,
    int M, int N, int K)
{
    __shared__ __align__(16) unsigned short lds[4][4096];  // Ah,Al,Bh,Bl: 8KB each

    const int tid  = threadIdx.x;
    const int lane = tid & 63;
    const int wid  = tid >> 6;
    const int wm = wid >> 1, wn = wid & 1;
    const int l15 = lane & 15, l4 = lane >> 4;
    const int brow = blockIdx.y * GBM;
    const int bcol = blockIdx.x * GBN;

    const int lhi  = lane >> 3;              // 0..7
    const int c8   = (lane & 7) ^ lhi;       // (g&7) == lhi for both chunks
    const int koff = (c8 & 3) * 8;           // element offset in k
    const int r0   = 32*wid + 2*lhi + (c8 >> 2);
    const int r1   = r0 + 16;
    const size_t a0 = (size_t)(brow + r0)*K + koff;
    const size_t a1 = (size_t)(brow + r1)*K + koff;
    const size_t b0 = (size_t)(bcol + r0)*K + koff;
    const size_t b1 = (size_t)(bcol + r1)*K + koff;
    char* lbase = (char*)&lds[0][0];
    const int cb0 = wid*2048, cb1 = wid*2048 + 1024;  // wave-uniform chunk bases

    const int ra = wm*64 + l15;
    const int ga = ra >> 1;
    const int abyte = ga*128 + (((((ra & 1) << 2) | l4) ^ (ga & 7)) << 4);
    const int rb = wn*64 + l15;
    const int gb = rb >> 1;
    const int bbyte = gb*128 + (((((rb & 1) << 2) | l4) ^ (gb & 7)) << 4);

    f32x4 acc[4][4] = {};

    for (int k0 = 0; k0 < K; k0 += GBK) {
        gload16(Ah  + a0 + k0, lbase         + cb0);
        gload16(Ah  + a1 + k0, lbase         + cb1);
        gload16(Al  + a0 + k0, lbase + 8192  + cb0);
        gload16(Al  + a1 + k0, lbase + 8192  + cb1);
        gload16(BhT + b0 + k0, lbase + 16384 + cb0);
        gload16(BhT + b1 + k0, lbase + 16384 + cb1);
        gload16(BlT + b0 + k0, lbase + 24576 + cb0);
        gload16(BlT + b1 + k0, lbase + 24576 + cb1);
        __syncthreads();

        short8 ah[4], al[4], bh[4], bl[4];
        #pragma unroll
        for (int m = 0; m < 4; ++m) {
            ah[m] = *(const short8*)(lbase         + abyte + m*1024);
            al[m] = *(const short8*)(lbase + 8192  + abyte + m*1024);
        }
        #pragma unroll
        for (int n = 0; n < 4; ++n) {
            bh[n] = *(const short8*)(lbase + 16384 + bbyte + n*1024);
            bl[n] = *(const short8*)(lbase + 24576 + bbyte + n*1024);
        }
        #pragma unroll
        for (int n = 0; n < 4; ++n)
            #pragma unroll
            for (int m = 0; m < 4; ++m) {
                acc[m][n] = __builtin_amdgcn_mfma_f32_16x16x32_bf16(ah[m], bh[n], acc[m][n], 0, 0, 0);
                acc[m][n] = __builtin_amdgcn_mfma_f32_16x16x32_bf16(ah[m], bl[n], acc[m][n], 0, 0, 0);
                acc[m][n] = __builtin_amdgcn_mfma_f32_16x16x32_bf16(al[m], bh[n], acc[m][n], 0, 0, 0);
            }
        __syncthreads();
    }

    #pragma unroll
    for (int n = 0; n < 4; ++n) {
        int col = bcol + wn*64 + n*16 + l15;
        float bv = bias[col];
        #pragma unroll
        for (int m = 0; m < 4; ++m) {
            int rbs = brow + wm*64 + m*16 + l4*4;
            #pragma unroll
            for (int r = 0; r < 4; ++r)
                C[(size_t)(rbs + r)*N + col] = acc[m][n][r] + bv;
        }
    }
}

// ---------------------------------------------------------------------------
// 3b) Fallback GEMM (in-kernel conversion, fp32 inputs) — Round-4 proven.
// ---------------------------------------------------------------------------
__global__ __launch_bounds__(256) void k_gemm_mfma(const float* __restrict__ A,
                                                   const float* __restrict__ B,
                                                   const float* __restrict__ bias,
                                                   float* __restrict__ C,
                                                   int M, int N, int K)
{
    __shared__ unsigned short As_hi[GBM][40];
    __shared__ unsigned short As_lo[GBM][40];
    __shared__ unsigned int   Bs[GBK][130];

    int tid  = threadIdx.x;
    int brow = blockIdx.y * GBM;
    int bcol = blockIdx.x * GBN;

    int lane = tid & 63;
    int wid  = tid >> 6;
    int wm   = wid >> 1;
    int wn   = wid & 1;
    int l15  = lane & 15;
    int l4   = lane >> 4;

    int a_m = tid >> 3;
    int a_c = tid & 7;
    int b_k = tid >> 5;
    int b_n = tid & 31;

    f32x4 acc[4][4] = {};

    for (int k0 = 0; k0 < K; k0 += GBK) {
        #pragma unroll
        for (int p = 0; p < 4; ++p) {
            int r = a_m + p*32;
            float4 v = *(const float4*)(A + (size_t)(brow + r)*K + k0 + a_c*4);
            unsigned h0 = pack_hi2(v.x, v.y);
            unsigned h1 = pack_hi2(v.z, v.w);
            float lx = v.x - hi_f32(v.x);
            float ly = v.y - hi_f32(v.y);
            float lz = v.z - hi_f32(v.z);
            float lw = v.w - hi_f32(v.w);
            unsigned l0 = pack_hi2(lx, ly);
            unsigned l1 = pack_hi2(lz, lw);
            *(uint2*)&As_hi[r][a_c*4] = make_uint2(h0, h1);
            *(uint2*)&As_lo[r][a_c*4] = make_uint2(l0, l1);
        }
        #pragma unroll
        for (int p = 0; p < 4; ++p) {
            int kk = b_k + p*8;
            float4 v = *(const float4*)(B + (size_t)(k0 + kk)*N + bcol + b_n*4);
            unsigned w0 = pack_pair(v.x);
            unsigned w1 = pack_pair(v.y);
            unsigned w2 = pack_pair(v.z);
            unsigned w3 = pack_pair(v.w);
            *(uint2*)&Bs[kk][b_n*4]     = make_uint2(w0, w1);
            *(uint2*)&Bs[kk][b_n*4 + 2] = make_uint2(w2, w3);
        }
        __syncthreads();

        short8 ah[4], al[4];
        #pragma unroll
        for (int m = 0; m < 4; ++m) {
            int r = wm*64 + m*16 + l15;
            ah[m] = *(const short8*)&As_hi[r][l4*8];
            al[m] = *(const short8*)&As_lo[r][l4*8];
        }

        #pragma unroll
        for (int n = 0; n < 4; ++n) {
            int col = wn*64 + n*16 + l15;
            unsigned w[8];
            #pragma unroll
            for (int j = 0; j < 8; ++j)
                w[j] = Bs[l4*8 + j][col];
            union { short8 v; unsigned d[4]; } bh, bl;
            #pragma unroll
            for (int d = 0; d < 4; ++d) {
                bh.d[d] = (w[2*d] >> 16)      | (w[2*d+1] & 0xFFFF0000u);
                bl.d[d] = (w[2*d] & 0xFFFFu)  | (w[2*d+1] << 16);
            }
            #pragma unroll
            for (int m = 0; m < 4; ++m) {
                acc[m][n] = __builtin_amdgcn_mfma_f32_16x16x32_bf16(ah[m], bh.v, acc[m][n], 0, 0, 0);
                acc[m][n] = __builtin_amdgcn_mfma_f32_16x16x32_bf16(ah[m], bl.v, acc[m][n], 0, 0, 0);
                acc[m][n] = __builtin_amdgcn_mfma_f32_16x16x32_bf16(al[m], bh.v, acc[m][n], 0, 0, 0);
            }
        }
        __syncthreads();
    }

    #pragma unroll
    for (int n = 0; n < 4; ++n) {
        int col = bcol + wn*64 + n*16 + l15;
        float bv = bias[col];
        #pragma unroll
        for (int m = 0; m < 4; ++m) {
            int rb = brow + wm*64 + m*16 + l4*4;
            #pragma unroll
            for (int r = 0; r < 4; ++r)
                C[(size_t)(rb + r)*N + col] = acc[m][n][r] + bv;
        }
    }
}

// ---------------------------------------------------------------------------
// 4) One LSTM timestep, v6: MFMA matvec.
//    Grid 256 blocks x 256 thr (4 waves). Block = 4 hidden cols x 4 gates
//    (16 gate-cols -> one 16x16 MFMA N-tile, mapped colL = gate*4 + jl).
//    Wave = K-quarter: 8 K-steps x {AhBh, AhBl, AlBh} split-bf16 MFMA,
//    2 accumulator streams. h carried as hi/lo bf16 ping-pong buffers
//    [16][1024] (rows 8..15 zero); W = W_hhT hi/lo [4096][1024] (L2-res).
//    Per-CU h traffic: 64 KB/step (vs 512 KB scalar) and no 48-shfl
//    butterfly. 4 K-quarter partials combined via 4 KB LDS; 32-thread tail
//    does activations, writes c, hs[t], and next h hi/lo.
//    Race-free: reads hbuf[(t+1)&1], writes hbuf[t&1] (disjoint).
// ---------------------------------------------------------------------------
__global__ __launch_bounds__(256) void k_lstm_step_mfma(
    const float* __restrict__ xg,
    const unsigned short* __restrict__ WhT_hi,
    const unsigned short* __restrict__ WhT_lo,
    const unsigned short* __restrict__ hp_hi,   // prev h, [16][1024], rows 8-15 = 0
    const unsigned short* __restrict__ hp_lo,
    unsigned short* __restrict__ hn_hi,         // next h (written rows 0-7)
    unsigned short* __restrict__ hn_lo,
    float* __restrict__ c_state,
    float* __restrict__ hs,
    int t)
{
    __shared__ float g_part[4][16][16];   // [kq][colL][row=batch]

    const int tid  = threadIdx.x;
    const int lane = tid & 63;
    const int kq   = tid >> 6;            // wave = K-quarter
    const int l15  = lane & 15;
    const int l4   = lane >> 4;
    const int j0   = blockIdx.x * 4;
    const int bcol = (l15 >> 2)*HID + j0 + (l15 & 3);  // W col for B-frag lane

    // tail-operand prefetch (consumed after the barrier)
    float xv0 = 0, xv1 = 0, xv2 = 0, xv3 = 0, cv = 0;
    const int tb = tid & 7;
    const int tj = (tid >> 3) & 3;
    if (tid < 32) {
        int jc = j0 + tj;
        size_t xbase = ((size_t)tb*SEQ + t)*GD + jc;
        xv0 = xg[xbase];
        xv1 = xg[xbase + HID];
        xv2 = xg[xbase + 2*HID];
        xv3 = xg[xbase + 3*HID];
        cv  = (t > 0) ? c_state[(size_t)tb*HID + jc] : 0.0f;
    }

    if (t > 0) {
        const int krow = l4*8;            // k offset inside a 32-wide K-step
        const unsigned short* wh = WhT_hi + (size_t)bcol*HID + krow;
        const unsigned short* wl = WhT_lo + (size_t)bcol*HID + krow;
        const unsigned short* ah = hp_hi  + (size_t)l15*HID + krow;
        const unsigned short* al = hp_lo  + (size_t)l15*HID + krow;

        f32x4 acc0 = {}, acc1 = {};       // 2 streams to break the dep chain
        #pragma unroll
        for (int ks = 0; ks < 8; ks += 2) {
            int ka = kq*256 + ks*32;
            int kb = ka + 32;
            short8 Ah0 = *(const short8*)(ah + ka);
            short8 Al0 = *(const short8*)(al + ka);
            short8 Bh0 = *(const short8*)(wh + ka);
            short8 Bl0 = *(const short8*)(wl + ka);
            short8 Ah1 = *(const short8*)(ah + kb);
            short8 Al1 = *(const short8*)(al + kb);
            short8 Bh1 = *(const short8*)(wh + kb);
            short8 Bl1 = *(const short8*)(wl + kb);
            acc0 = __builtin_amdgcn_mfma_f32_16x16x32_bf16(Ah0, Bh0, acc0, 0, 0, 0);
            acc1 = __builtin_amdgcn_mfma_f32_16x16x32_bf16(Ah1, Bh1, acc1, 0, 0, 0);
            acc0 = __builtin_amdgcn_mfma_f32_16x16x32_bf16(Ah0, Bl0, acc0, 0, 0, 0);
            acc1 = __builtin_amdgcn_mfma_f32_16x16x32_bf16(Ah1, Bl1, acc1, 0, 0, 0);
            acc0 = __builtin_amdgcn_mfma_f32_16x16x32_bf16(Al0, Bh0, acc0, 0, 0, 0);
            acc1 = __builtin_amdgcn_mfma_f32_16x16x32_bf16(Al1, Bh1, acc1, 0, 0, 0);
        }
        f32x4 acc = acc0 + acc1;
        // C/D: col = l15, row = l4*4 + r (row = batch; rows 8-15 are pad)
        *(f32x4*)&g_part[kq][l15][l4*4] = acc;
    }
    __syncthreads();

    if (tid < 32) {
        int jc = j0 + tj;
        float sv[4];
        #pragma unroll
        for (int g = 0; g < 4; ++g) {
            int colL = g*4 + tj;
            sv[g] = (t > 0) ? (g_part[0][colL][tb] + g_part[1][colL][tb]
                             + g_part[2][colL][tb] + g_part[3][colL][tb])
                            : 0.0f;
        }
        float iv = sv[0] + xv0;
        float fv = sv[1] + xv1;
        float gv = sv[2] + xv2;
        float ov = sv[3] + xv3;
        iv = 1.0f / (1.0f + expf(-iv));
        fv = 1.0f / (1.0f + expf(-fv));
        gv = tanhf(gv);
        ov = 1.0f / (1.0f + expf(-ov));
        float cn = fv*cv + iv*gv;
        float hn = ov * tanhf(cn);
        c_state[(size_t)tb*HID + jc] = cn;
        hs[((size_t)tb*SEQ + t)*HID + jc] = hn;
        unsigned hb = __float_as_uint(hn) & 0xFFFF0000u;
        hn_hi[(size_t)tb*HID + jc] = (unsigned short)(hb >> 16);
        hn_lo[(size_t)tb*HID + jc] =
            (unsigned short)(__float_as_uint(hn - __uint_as_float(hb)) >> 16);
    }
}

// ---------------------------------------------------------------------------
// Launch
// ---------------------------------------------------------------------------
extern "C" void kernel_launch(void* const* d_in, const int* in_sizes, int n_in,
                              void* d_out, int out_size, void* d_ws, size_t ws_size,
                              hipStream_t stream)
{
    const int*   ids    = (const int*)  d_in[0];
    const float* w_out  = (const float*)d_in[1];
    const float* b_out  = (const float*)d_in[2];
    const float* W_ih   = (const float*)d_in[3];
    const float* W_hh   = (const float*)d_in[4];
    const float* b_lstm = (const float*)d_in[5];
    float* out = (float*)d_out;

    // d_out scratch (524 MB): every region dead before the final GEMM writes C.
    char* ob = (char*)d_out;
    unsigned short* emb_hi  = (unsigned short*)(ob);               //  8,388,608 B
    unsigned short* emb_lo  = (unsigned short*)(ob + 8388608);     //  8,388,608 B
    unsigned short* whh_hiT = (unsigned short*)(ob + 16777216);    //  8,388,608 B
    unsigned short* whh_loT = (unsigned short*)(ob + 25165824);    //  8,388,608 B
    float*          xg      = (float*)(ob + 33554432);             // 67,108,864 B
    float*          cstate  = (float*)(ob + 100663296);            //     32,768 B
    unsigned short* wih_hiT = (unsigned short*)(ob + 100696064);   //  8,388,608 B
    unsigned short* wih_loT = (unsigned short*)(ob + 109084672);   //  8,388,608 B
    float*          hs_dout = (float*)(ob + 117473280);            // 16,777,216 B
    unsigned short* hb0_hi  = (unsigned short*)(ob + 134250496);   //     32,768 B
    unsigned short* hb0_lo  = (unsigned short*)(ob + 134283264);   //     32,768 B
    unsigned short* hb1_hi  = (unsigned short*)(ob + 134316032);   //     32,768 B
    unsigned short* hb1_lo  = (unsigned short*)(ob + 134348800);   //     32,768 B

    // d_ws: fast path needs hs_hi/lo + w_out^T hi/lo = 147,849,216 B.
    char* wb = (char*)d_ws;
    const size_t NEED = 147849216ull;
    const bool big_ws = (ws_size >= NEED);
    unsigned short* hs_hi  = (unsigned short*)(wb);                //  8,388,608 B
    unsigned short* hs_lo  = (unsigned short*)(wb + 8388608);      //  8,388,608 B
    unsigned short* wo_hiT = (unsigned short*)(wb + 16777216);     // 65,536,000 B
    unsigned short* wo_loT = (unsigned short*)(wb + 82313216);     // 65,536,000 B
    float* hs = big_ws ? hs_dout : (float*)wb;

    // 1) embedding gather (split to hi/lo bf16)
    k_gather_split<<<ROWS, 256, 0, stream>>>(ids, w_out, emb_hi, emb_lo);

    // 2) W_hh -> transposed hi/lo bf16 [4096][1024] (scan B-operand)
    k_transsplit<<<dim3(GD/32, HID/32), dim3(32, 8), 0, stream>>>(
        W_hh, whh_hiT, whh_loT, GD);

    // 2b) W_ih -> transposed hi/lo bf16 [4096][1024]
    k_transsplit<<<dim3(GD/32, HID/32), dim3(32, 8), 0, stream>>>(
        W_ih, wih_hiT, wih_loT, GD);

    // 2c) zero the h ping-pong buffers (131072 B = 8192 uint4)
    k_zero16<<<32, 256, 0, stream>>>((uint4*)hb0_hi, 8192);

    // 3) x_gates = emb @ W_ih + b_lstm  (K-major fast MFMA GEMM)
    k_gemm_fast<<<dim3(GD/GBN, ROWS/GBM), 256, 0, stream>>>(
        emb_hi, emb_lo, wih_hiT, wih_loT, b_lstm, xg, ROWS, GD, HID);

    // 4) sequential MFMA scan: 512 launches, ping-pong h hi/lo buffers
    for (int t = 0; t < SEQ; ++t) {
        unsigned short* rd_hi = (t & 1) ? hb0_hi : hb1_hi;  // read  = buf[(t+1)&1]
        unsigned short* rd_lo = (t & 1) ? hb0_lo : hb1_lo;
        unsigned short* wr_hi = (t & 1) ? hb1_hi : hb0_hi;  // write = buf[t&1]
        unsigned short* wr_lo = (t & 1) ? hb1_lo : hb0_lo;
        k_lstm_step_mfma<<<HID/4, 256, 0, stream>>>(
            xg, whh_hiT, whh_loT, rd_hi, rd_lo, wr_hi, wr_lo, cstate, hs, t);
    }

    // 5) logits = hs @ w_out + b_out
    if (big_ws) {
        k_transsplit<<<dim3(VOCAB/32, HID/32), dim3(32, 8), 0, stream>>>(
            w_out, wo_hiT, wo_loT, VOCAB);
        k_split_f32<<<1024, 256, 0, stream>>>(hs, hs_hi, hs_lo, (long)ROWS*HID/4);
        k_gemm_fast<<<dim3(VOCAB/GBN, ROWS/GBM), 256, 0, stream>>>(
            hs_hi, hs_lo, wo_hiT, wo_loT, b_out, out, ROWS, VOCAB, HID);
    } else {
        k_gemm_mfma<<<dim3(VOCAB/GBN, ROWS/GBM), 256, 0, stream>>>(
            hs, w_out, b_out, out, ROWS, VOCAB, HID);
    }
}